// Round 12
// baseline (2671.144 us; speedup 1.0000x reference)
//
#include <hip/hip_runtime.h>
#include <cstdint>
#include <cstddef>

#define T_TOK 4096
#define DIM   768
#define VOCAB 32000
#define NLAYER 4
#define HALF_TV 65536000u   // T*V/2

typedef short bf16x8 __attribute__((ext_vector_type(8)));
typedef float f32x4  __attribute__((ext_vector_type(4)));
typedef float f32x4v __attribute__((ext_vector_type(4)));

// ---------------- threefry2x32 (exact JAX semantics) ----------------
__host__ __device__ inline void tf2x32(uint32_t k0, uint32_t k1, uint32_t& v0, uint32_t& v1){
  uint32_t ks2 = k0 ^ k1 ^ 0x1BD11BDAu;
  uint32_t x0 = v0 + k0, x1 = v1 + k1;
#define TFR(R) { x0 += x1; x1 = (x1<<R)|(x1>>(32-R)); x1 ^= x0; }
  TFR(13) TFR(15) TFR(26) TFR(6)
  x0 += k1;  x1 += ks2 + 1u;
  TFR(17) TFR(29) TFR(16) TFR(24)
  x0 += ks2; x1 += k0 + 2u;
  TFR(13) TFR(15) TFR(26) TFR(6)
  x0 += k0;  x1 += k1 + 3u;
  TFR(17) TFR(29) TFR(16) TFR(24)
  x0 += k1;  x1 += ks2 + 4u;
  TFR(13) TFR(15) TFR(26) TFR(6)
  x0 += ks2; x1 += k0 + 5u;
#undef TFR
  v0 = x0; v1 = x1;
}

// -ln(u) with RELATIVE accuracy, u = k ? k*2^-23 : FLT_MIN.
__device__ inline float neglog_u(uint32_t k){
  float L;
  if (k >= 0x780000u){
    float x = (float)(0x800000u - k) * 1.1920928955078125e-7f;   // 1-u, exact
    L = x * fmaf(x, fmaf(x, fmaf(x, 0.25f, 0.3333333333333f), 0.5f), 1.0f);
  } else {
    float l2k = __builtin_amdgcn_logf((float)k);                 // log2(k)
    L = 0.69314718055994531f * (23.0f - l2k);
    if (k == 0u) L = 87.33654475055310898f;                      // 126*ln2
  }
  return L;
}

__device__ inline void gumbel_pair(uint32_t kf0, uint32_t kf1, uint32_t t_up, uint32_t v,
                                   float& gu, float& gd){
  uint32_t m = t_up * (uint32_t)VOCAB + v;
  uint32_t x0 = m, x1 = m + HALF_TV;
  tf2x32(kf0, kf1, x0, x1);
  float Lu = neglog_u(x0 >> 9);
  float Ld = neglog_u(x1 >> 9);
  gu = -0.69314718055994531f * __builtin_amdgcn_logf(Lu);
  gd = -0.69314718055994531f * __builtin_amdgcn_logf(Ld);
}

// ---------------- helpers ----------------
__device__ inline unsigned short f2bf(float f){  // RNE f32->bf16
  uint32_t u = __float_as_uint(f);
  return (unsigned short)((u + 0x7FFFu + ((u >> 16) & 1u)) >> 16);
}
__device__ inline float bf2f(unsigned short h){
  return __uint_as_float(((uint32_t)h) << 16);
}
__device__ inline void cvt8(const float* f, bool lo, unsigned short* out){
  #pragma unroll
  for (int e=0;e<8;e++){
    float x = f[e];
    unsigned short h = f2bf(x);
    if (lo) h = f2bf(x - bf2f(h));
    out[e] = h;
  }
}
__device__ inline float blockReduceSum(float v){
  __shared__ float red[4];
  #pragma unroll
  for (int off=32; off>0; off>>=1) v += __shfl_down(v, off);
  int w = threadIdx.x >> 6;
  __syncthreads();
  if ((threadIdx.x & 63) == 0) red[w] = v;
  __syncthreads();
  return red[0] + red[1] + red[2] + red[3];
}

__device__ inline void gload16(const void* g, void* l){
  __builtin_amdgcn_global_load_lds(
      (const __attribute__((address_space(1))) unsigned int*)g,
      (__attribute__((address_space(3))) unsigned int*)l, 16, 0, 0);
}

enum { ST_F32 = 0, ST_HILO = 1, ST_SAMPLE = 2 };

// =====================================================================
// k_hgemm256: PERSISTENT 256x256-tile GEMM, 1024 threads = 16 waves
// (4M x 4N), wave C = 64x64, 4 waves/SIMD.  Double-buffered 128KB LDS,
// tile t+1 staged at tile-t start, ONE barrier per K-tile, XOR swizzle
// (conflict-free, PMC=0).  Persistent (256 blocks = 1/CU full
// residency): each block sweeps s += nloc keeping ONE bm (A-panel
// L2-resident per XCD); next super-tile's stage(0) issued BEFORE the
// epilogue (HBM latency hides under epilogue VALU).
// r12: BATCHED fragment loads — bv(k0),av(k0),bv(k1) issued as one
// 12-read burst so bv(k1) latency hides under k0's MFMA cluster
// (r8-r11 measured per-tile time == serial LDS+MFMA sum; short
// alternating bursts kept all 4 waves/SIMD in the same rhythm).
// MFMA order per accumulator unchanged (k0 then k1) -> bit-identical.
// r9 refutation: no per-phase block-wide barriers (homogeneous wave
// roles -> they serialize ds_read vs MFMA; free-running TLP wins).
// M rows slab-interleaved {t, t+2048} at 16-row granularity.
// =====================================================================
template<int KSTEPS, int NSEG, int STORE, bool NTST, bool BIAS, bool QGELU>
__global__ __launch_bounds__(1024, 4) void k_hgemm256(
    const unsigned short* __restrict__ A0, const unsigned short* __restrict__ A1,
    const unsigned short* __restrict__ B0, const unsigned short* __restrict__ B2,
    float* __restrict__ C, unsigned short* __restrict__ Ch, unsigned short* __restrict__ Cl,
    const float* __restrict__ bias, uint32_t kf0, uint32_t kf1,
    unsigned long long* __restrict__ row_best, int N, int SMAX)
{
  constexpr int K  = KSTEPS * 64;
  constexpr int NT = NSEG * KSTEPS;
  __shared__ unsigned short sAll[65536];   // 2 buf x (A 32KB + B 32KB) = 128 KB

  const int t = threadIdx.x;
  const int w = t >> 6, l = t & 63;
  const int wm = w >> 2, wn = w & 3;       // 4M x 4N waves
  const int g = l >> 4, r = l & 15;

  const int xcd  = blockIdx.x & 7;
  const int nloc = gridDim.x >> 3;
  const int lcl  = blockIdx.x >> 3;

  // lane-invariant staging row bases (tile-local)
  int abase[2], nbase[2];
  #pragma unroll
  for (int p=0;p<2;p++){
    int mr = p*128 + (t >> 3);             // tile-local row 0..255
    int blk = mr >> 4;
    abase[p] = ((blk>>1)<<4) + (mr & 15) + ((blk & 1) ? 2048 : 0);
    nbase[p] = p*128 + (t >> 3);
  }
  const int swz  = ((t & 7) ^ ((t >> 3) & 7)) << 3;   // pre-swizzled k-chunk
  const int ldst = t * 16;                              // lane-linear LDS bytes

  auto stage = [&](int vt, int bm_, int bn_){
    char* base = (char*)sAll + (vt & 1) * 65536;
    int seg = (NSEG == 1) ? 0 : (vt / KSTEPS);
    int k0  = ((NSEG == 1) ? vt : (vt % KSTEPS)) * 64;
    const unsigned short* Ap = (seg == 1) ? A1 : A0;
    const unsigned short* Bp = (seg == 2) ? B2 : B0;
    #pragma unroll
    for (int p=0;p<2;p++)
      gload16(Ap + (size_t)(bm_*128 + abase[p]) * K + k0 + swz, base + p*16384 + ldst);
    #pragma unroll
    for (int p=0;p<2;p++)
      gload16(Bp + (size_t)(bn_*256 + nbase[p]) * K + k0 + swz, base + 32768 + p*16384 + ldst);
  };

  int s = lcl;
  if (s >= SMAX) return;
  int bm = xcd*2 + (s & 1), bn = s >> 1;
  stage(0, bm, bn);
  __syncthreads();                          // first tile resident

  while (true) {
    f32x4 acc[4][4] = {};
    for (int vt = 0; vt < NT; ++vt){
      if (vt + 1 < NT) stage(vt + 1, bm, bn);   // full-tile prefetch lead
      const char* sA = (const char*)sAll + (vt & 1) * 65536;
      const char* sB = sA + 32768;
      bf16x8 bv0[4], av0[4], bv1[4], av1[4];
      #pragma unroll
      for (int ni=0;ni<4;ni++){
        int tr = wn*64 + ni*16 + r;
        bv0[ni] = *(const bf16x8*)(sB + tr*128 + ((g ^ (r&7))<<4));
      }
      #pragma unroll
      for (int q=0;q<4;q++){
        int tr = wm*64 + q*16 + r;
        av0[q] = *(const bf16x8*)(sA + tr*128 + ((g ^ (r&7))<<4));
      }
      #pragma unroll
      for (int ni=0;ni<4;ni++){
        int tr = wn*64 + ni*16 + r;
        bv1[ni] = *(const bf16x8*)(sB + tr*128 + (((4+g) ^ (r&7))<<4));
      }
      __builtin_amdgcn_s_setprio(1);
      #pragma unroll
      for (int q=0;q<4;q++)
        #pragma unroll
        for (int ni=0;ni<4;ni++)
          acc[q][ni] = __builtin_amdgcn_mfma_f32_16x16x32_bf16(av0[q], bv0[ni], acc[q][ni], 0, 0, 0);
      __builtin_amdgcn_s_setprio(0);
      #pragma unroll
      for (int q=0;q<4;q++){
        int tr = wm*64 + q*16 + r;
        av1[q] = *(const bf16x8*)(sA + tr*128 + (((4+g) ^ (r&7))<<4));
      }
      __builtin_amdgcn_s_setprio(1);
      #pragma unroll
      for (int q=0;q<4;q++)
        #pragma unroll
        for (int ni=0;ni<4;ni++)
          acc[q][ni] = __builtin_amdgcn_mfma_f32_16x16x32_bf16(av1[q], bv1[ni], acc[q][ni], 0, 0, 0);
      __builtin_amdgcn_s_setprio(0);
      __syncthreads();                      // vmcnt+lgkm drain + barrier
    }

    // Prefetch the NEXT super-tile's first K-tile BEFORE the epilogue:
    // epilogue VALU fully hides the HBM latency.  buf0's last reader was
    // vt=NT-2 (NT even), already barrier-separated -> safe.
    int ns = s + nloc;
    bool more = (ns < SMAX);
    int nbm = 0, nbn = 0;
    if (more){ nbm = xcd*2 + (ns & 1); nbn = ns >> 1; stage(0, nbm, nbn); }

    if constexpr (STORE == ST_SAMPLE){
      #pragma unroll
      for (int mi=0; mi<4; mi+=2){
        int row16 = (wm*2 + (mi>>1)) * 16;  // even fragment -> up slab
        #pragma unroll
        for (int jj=0;jj<4;jj++){
          uint32_t t_up = bm*128 + row16 + g*4 + jj;   // < 2048
          unsigned long long bu = 0ull, bd = 0ull;
          #pragma unroll
          for (int ni=0;ni<4;ni++){
            uint32_t v = bn*256 + wn*64 + ni*16 + r;
            float gu, gd;
            gumbel_pair(kf0, kf1, t_up, v, gu, gd);
            float vu = acc[mi][ni][jj]   + gu;
            float vd = acc[mi+1][ni][jj] + gd;
            uint32_t fu = __float_as_uint(vu); fu = (fu & 0x80000000u) ? ~fu : (fu | 0x80000000u);
            uint32_t fd = __float_as_uint(vd); fd = (fd & 0x80000000u) ? ~fd : (fd | 0x80000000u);
            unsigned long long pu = ((unsigned long long)fu << 32) | (unsigned long long)(~v);
            unsigned long long pd = ((unsigned long long)fd << 32) | (unsigned long long)(~v);
            if (pu > bu) bu = pu;
            if (pd > bd) bd = pd;
          }
          #pragma unroll
          for (int off=1; off<16; off<<=1){
            unsigned int l0 = (unsigned int)bu, h0 = (unsigned int)(bu>>32);
            unsigned int l1 = __shfl_xor(l0, off), h1 = __shfl_xor(h0, off);
            unsigned long long o = ((unsigned long long)h1 << 32) | (unsigned long long)l1;
            if (o > bu) bu = o;
            l0 = (unsigned int)bd; h0 = (unsigned int)(bd>>32);
            l1 = __shfl_xor(l0, off); h1 = __shfl_xor(h0, off);
            o = ((unsigned long long)h1 << 32) | (unsigned long long)l1;
            if (o > bd) bd = o;
          }
          if (r == 0){
            atomicMax(&row_best[t_up], bu);
            atomicMax(&row_best[t_up + 2048], bd);
          }
        }
      }
    } else {
      #pragma unroll
      for (int mi=0;mi<4;mi++){
        int fb = wm*4 + mi;
        int mbase = bm*128 + ((fb>>1)<<4) + ((fb & 1) ? 2048 : 0);
        #pragma unroll
        for (int ni=0;ni<4;ni++){
          int n = bn*256 + wn*64 + ni*16 + r;
          float bv_ = BIAS ? bias[n] : 0.0f;
          #pragma unroll
          for (int jj=0;jj<4;jj++){
            int m = mbase + g*4 + jj;
            float v = acc[mi][ni][jj] + bv_;
            if constexpr (QGELU) v = v / (1.0f + expf(-1.702f * v));
            if constexpr (STORE == ST_F32){
              if constexpr (NTST) __builtin_nontemporal_store(v, &C[(size_t)m * N + n]);
              else                C[(size_t)m * N + n] = v;
            } else {
              unsigned short h = f2bf(v);
              Ch[(size_t)m * N + n] = h;
              Cl[(size_t)m * N + n] = f2bf(v - bf2f(h));
            }
          }
        }
      }
    }

    if (!more) return;
    __syncthreads();                        // next tile's stage(0) visible
    s = ns; bm = nbm; bn = nbn;
  }
}

// =====================================================================
// k_hgemm_seg: 128^2-tile dbuf GEMM, ONE split-bf16 segment per block
// (seg0 = Ah*Bh, seg1 = Al*Bh, seg2 = Ah*Bl) -> f32 partials; 3x grid
// => full chip for small-N shapes (proj/op).  Deterministic reduce in
// k_redln (order p0+p1+p2).
// =====================================================================
template<int KSTEPS>
__global__ __launch_bounds__(256) void k_hgemm_seg(
    const unsigned short* __restrict__ Ah, const unsigned short* __restrict__ Al,
    const unsigned short* __restrict__ Bh, const unsigned short* __restrict__ Bl,
    float* __restrict__ Part, int N)
{
  constexpr int K  = KSTEPS * 64;
  constexpr int NT = KSTEPS;
  __shared__ unsigned short sAll[2 * 16 * 1024];   // 2 buf x (A 16KB + B 16KB)

  const int t = threadIdx.x;
  const int wave = t >> 6, lane = t & 63;
  const int wm = wave >> 1, wn = wave & 1;
  const int g = lane >> 4, r = lane & 15;
  const int lr = lane >> 3, lc = lane & 7;

  int bps = (N >> 7) * 32;                  // blocks per seg
  int seg = blockIdx.x / bps;
  int bid = blockIdx.x % bps;
  const unsigned short* Ap = (seg == 1) ? Al : Ah;
  const unsigned short* Bp = (seg == 2) ? Bl : Bh;
  float* C = Part + (size_t)seg * T_TOK * N;

  int xcd = bid & 7, c = bid >> 3;
  int bm = xcd*4 + (c & 3);
  int bn = c >> 2;

  f32x4 acc[4][4] = {};

  size_t arow[4], brow[4];
  #pragma unroll
  for (int p=0;p<4;p++){
    int mr = p*32 + wave*8 + lr;
    int blk = mr >> 4;
    arow[p] = (size_t)(bm*64 + ((blk>>1)<<4) + (mr & 15) + ((blk & 1) ? 2048 : 0)) * K;
    brow[p] = (size_t)(bn*128 + mr) * K;
  }
  const int swz  = (lc ^ lr) << 3;
  const int ldst = (wave*8 + lr)*128 + lc*16;

  auto stage = [&](int vt){
    char* base = (char*)sAll + (vt & 1) * 32768;
    int k0 = vt * 64;
    #pragma unroll
    for (int p=0;p<4;p++){
      gload16(Ap + arow[p] + k0 + swz, base + p*4096 + ldst);
      gload16(Bp + brow[p] + k0 + swz, base + 16384 + p*4096 + ldst);
    }
  };

  stage(0);
  __syncthreads();

  for (int vt = 0; vt < NT; ++vt){
    if (vt + 1 < NT) stage(vt + 1);
    const char* sA = (const char*)sAll + (vt & 1) * 32768;
    const char* sB = sA + 16384;
    #pragma unroll
    for (int kk=0;kk<2;kk++){
      bf16x8 av[4], bv[4];
      #pragma unroll
      for (int mi=0;mi<4;mi++){
        int tr = wm*64 + mi*16 + r;
        av[mi] = *(const bf16x8*)(sA + tr*128 + (((kk*4+g) ^ (r&7))<<4));
      }
      #pragma unroll
      for (int ni=0;ni<4;ni++){
        int tr = wn*64 + ni*16 + r;
        bv[ni] = *(const bf16x8*)(sB + tr*128 + (((kk*4+g) ^ (r&7))<<4));
      }
      #pragma unroll
      for (int mi=0;mi<4;mi++)
        #pragma unroll
        for (int ni=0;ni<4;ni++)
          acc[mi][ni] = __builtin_amdgcn_mfma_f32_16x16x32_bf16(av[mi], bv[ni], acc[mi][ni], 0, 0, 0);
    }
    __syncthreads();
  }

  #pragma unroll
  for (int mi=0;mi<4;mi++){
    int blk2 = wm*4 + mi;
    int mbase = bm*64 + ((blk2>>1)<<4) + ((blk2 & 1) ? 2048 : 0);
    #pragma unroll
    for (int ni=0;ni<4;ni++){
      int n = bn*128 + wn*64 + ni*16 + r;
      #pragma unroll
      for (int jj=0;jj<4;jj++){
        int m = mbase + g*4 + jj;
        C[(size_t)m * N + n] = acc[mi][ni][jj];
      }
    }
  }
}

// =====================================================================
// k_redln: deterministic seg-sum + bias (+res) + LayerNorm, fused.
// =====================================================================
__global__ __launch_bounds__(256) void k_redln(
    const float* __restrict__ P, const float* __restrict__ bias,
    const float* __restrict__ res,
    const float* __restrict__ g, const float* __restrict__ b,
    float* __restrict__ X, unsigned short* __restrict__ Xbf,
    unsigned short* __restrict__ Xlo)
{
  const size_t TD1 = (size_t)T_TOK * DIM;
  int row = blockIdx.x;
  float v[3];
  #pragma unroll
  for (int jj=0;jj<3;jj++){
    int d = threadIdx.x + jj*256;
    size_t o = (size_t)row*DIM + d;
    float x = P[o] + P[TD1 + o] + P[2*TD1 + o] + bias[d];
    if (res) x += res[o];
    v[jj] = x;
  }
  float s = blockReduceSum(v[0]+v[1]+v[2]);
  float mean = s * (1.0f/DIM);
  float s2 = 0;
  #pragma unroll
  for (int jj=0;jj<3;jj++){ float d = v[jj]-mean; s2 += d*d; }
  s2 = blockReduceSum(s2);
  float rs = rsqrtf(s2 * (1.0f/DIM) + 1e-5f);
  #pragma unroll
  for (int jj=0;jj<3;jj++){
    int d = threadIdx.x + jj*256;
    size_t o = (size_t)row*DIM + d;
    float out = (v[jj]-mean)*rs*g[d] + b[d];
    X[o] = out;
    unsigned short h = f2bf(out);
    Xbf[o] = h;
    Xlo[o] = f2bf(out - bf2f(h));
  }
}

// ---------------- weight transpose + f32->bf16 (hi[/lo]) ----------------
template<bool SPLIT>
__global__ __launch_bounds__(256) void k_wt_t(const float* __restrict__ W,
    unsigned short* __restrict__ Bh, unsigned short* __restrict__ Bl, int K, int N)
{
  __shared__ unsigned short sH[64][72];
  __shared__ unsigned short sL[64][72];
  int kt = blockIdx.x, nt = blockIdx.y;
  int t = threadIdx.x;
  int kr = t >> 4, nc4 = (t & 15) * 4;
  #pragma unroll
  for (int p=0;p<4;p++){
    int k = p*16 + kr;
    f32x4v w = __builtin_nontemporal_load((const f32x4v*)&W[(size_t)(kt*64 + k) * N + nt*64 + nc4]);
    #pragma unroll
    for (int e=0;e<4;e++){
      unsigned short h = f2bf(w[e]);
      sH[nc4+e][k] = h;
      if (SPLIT) sL[nc4+e][k] = f2bf(w[e] - bf2f(h));
    }
  }
  __syncthreads();
  #pragma unroll
  for (int q=0;q<2;q++){
    int cid = t + q*256;
    int n = cid >> 3, ch = cid & 7;
    *(bf16x8*)&Bh[(size_t)(nt*64+n)*K + kt*64 + ch*8] = *(const bf16x8*)&sH[n][ch*8];
    if (SPLIT)
      *(bf16x8*)&Bl[(size_t)(nt*64+n)*K + kt*64 + ch*8] = *(const bf16x8*)&sL[n][ch*8];
  }
}

// ---------------- embed + LN ----------------
__global__ __launch_bounds__(256) void k_embed_ln(const int* __restrict__ idx,
    const float* __restrict__ wte, const float* __restrict__ g, const float* __restrict__ b,
    float* __restrict__ Xraw, unsigned short* __restrict__ Hh, unsigned short* __restrict__ Hl)
{
  int row = blockIdx.x;
  const float* src = wte + (size_t)idx[row] * DIM;
  float v[3];
  #pragma unroll
  for (int jj=0;jj<3;jj++) v[jj] = src[threadIdx.x + jj*256];
  float s = blockReduceSum(v[0]+v[1]+v[2]);
  float mean = s * (1.0f/DIM);
  float s2 = 0;
  #pragma unroll
  for (int jj=0;jj<3;jj++){ float d = v[jj]-mean; s2 += d*d; }
  s2 = blockReduceSum(s2);
  float rs = rsqrtf(s2 * (1.0f/DIM) + 1e-5f);
  #pragma unroll
  for (int jj=0;jj<3;jj++){
    int d = threadIdx.x + jj*256;
    Xraw[(size_t)row*DIM + d] = v[jj];
    float o = (v[jj]-mean)*rs*g[d] + b[d];
    unsigned short h = f2bf(o);
    Hh[(size_t)row*DIM + d] = h;
    Hl[(size_t)row*DIM + d] = f2bf(o - bf2f(h));
  }
}

// ---------------- mask compaction ----------------
__global__ void k_mask(const unsigned long long* __restrict__ row_best,
    const int* __restrict__ idx, int j, int* __restrict__ count, int* __restrict__ plist)
{
  int t = blockIdx.x * blockDim.x + threadIdx.x;
  if (t >= T_TOK) return;
  int v = (int)(~(uint32_t)(row_best[t] & 0xFFFFFFFFull));
  int tgt = (t < T_TOK-1) ? idx[t+1] : -1;
  if (v == tgt && t < T_TOK - j){
    int pos = atomicAdd(count, 1);
    plist[pos] = t;
  }
}

// ---------------- sparse merge MLP ----------------
__global__ __launch_bounds__(256) void k_merge(const float* __restrict__ X,
    const int* __restrict__ plist, const int* __restrict__ count,
    const float* __restrict__ lng, const float* __restrict__ lnb,
    const float* __restrict__ fcw, const float* __restrict__ fcb,
    const float* __restrict__ pjw, const float* __restrict__ pjb,
    float* __restrict__ mergebuf, int j)
{
  __shared__ float sh[1536 + 3072];
  int nb = *count;
  for (int bIdx = blockIdx.x; bIdx < nb; bIdx += gridDim.x){
    int p = plist[bIdx];
    const float* xp = X + (size_t)p * DIM;
    const float* x2 = X + (size_t)(p + j) * DIM;
    for (int d = threadIdx.x; d < 1536; d += 256)
      sh[d] = (d < DIM) ? xp[d] : x2[d - DIM];
    __syncthreads();
    float s = 0;
    for (int d = threadIdx.x; d < 1536; d += 256) s += sh[d];
    s = blockReduceSum(s);
    float mean = s * (1.0f/1536.0f);
    float s2 = 0;
    for (int d = threadIdx.x; d < 1536; d += 256){ float df = sh[d]-mean; s2 += df*df; }
    s2 = blockReduceSum(s2);
    float rs = rsqrtf(s2 * (1.0f/1536.0f) + 1e-5f);
    __syncthreads();
    for (int d = threadIdx.x; d < 1536; d += 256)
      sh[d] = (sh[d]-mean)*rs*lng[d] + lnb[d];
    __syncthreads();
    float* act = sh + 1536;
    #pragma unroll
    for (int jj=0;jj<12;jj++){
      int n = threadIdx.x + jj*256;
      float a = fcb[n];
      for (int k=0;k<1536;k++) a += sh[k]*fcw[(size_t)k*3072 + n];
      act[n] = a / (1.0f + expf(-1.702f*a));
    }
    __syncthreads();
    #pragma unroll
    for (int jj=0;jj<3;jj++){
      int d = threadIdx.x + jj*256;
      float a = pjb[d];
      for (int k=0;k<3072;k++) a += act[k]*pjw[(size_t)k*DIM + d];
      mergebuf[(size_t)bIdx*DIM + d] = x2[d] + a;
    }
    __syncthreads();
  }
}

__global__ void k_scatter(float* __restrict__ X, unsigned short* __restrict__ Xbf,
    unsigned short* __restrict__ Xlo, const float* __restrict__ mergebuf,
    const int* __restrict__ plist, const int* __restrict__ count, int j)
{
  int nb = *count;
  for (int bIdx = blockIdx.x; bIdx < nb; bIdx += gridDim.x){
    int p = plist[bIdx];
    for (int d = threadIdx.x; d < DIM; d += 256){
      float v = mergebuf[(size_t)bIdx*DIM + d];
      size_t o = (size_t)(p + j)*DIM + d;
      X[o] = v;
      unsigned short h = f2bf(v);
      Xbf[o] = h;
      Xlo[o] = f2bf(v - bf2f(h));
    }
  }
}

// ---------------- fallback final-head GEMM (f32 in, split-bf16) ----
__global__ __launch_bounds__(256) void k_gemm_old(
    const float* __restrict__ A, const float* __restrict__ B, float* __restrict__ C,
    int M, int N, int K)
{
  __shared__ unsigned short sA[128*64];
  __shared__ unsigned short sB[128*64];
  const int t = threadIdx.x;
  const int bn = blockIdx.x, bm = blockIdx.y;
  const int wave = t >> 6, lane = t & 63;
  const int wm = wave >> 1, wn = wave & 1;
  const int g = lane >> 4, r = lane & 15;
  f32x4 acc[4][4] = {};
  const int nK = K >> 6;
  const int aC = t & 7,  aM0 = t >> 3;
  const int bN0 = t & 31, bC = t >> 5;
  const float* Abase = A + (size_t)(bm*128) * K;
  const float* Bbase = B + (size_t)(bn*128);
  for (int seg = 0; seg < 3; ++seg) {
    const bool aLO = (seg == 1), bLO = (seg == 2);
    for (int kb = 0; kb < nK; ++kb) {
      const int k0 = kb << 6;
      __syncthreads();
      #pragma unroll
      for (int p=0;p<4;p++){
        int m = p*32 + aM0;
        const float* src = Abase + (size_t)m * K + k0 + aC*8;
        float ff[8];
        *(float4*)(ff)   = *(const float4*)(src);
        *(float4*)(ff+4) = *(const float4*)(src+4);
        unsigned short hh[8];
        cvt8(ff, aLO, hh);
        *(bf16x8*)&sA[m*64 + ((aC ^ (m & 7)) * 8)] = *(bf16x8*)hh;
      }
      #pragma unroll
      for (int p=0;p<4;p++){
        int n = p*32 + bN0;
        float ff[8];
        const float* src = Bbase + (size_t)(k0 + bC*8) * N + n;
        #pragma unroll
        for (int e=0;e<8;e++) ff[e] = src[(size_t)e * N];
        unsigned short hh[8];
        cvt8(ff, bLO, hh);
        *(bf16x8*)&sB[n*64 + ((bC ^ (n & 7)) * 8)] = *(bf16x8*)hh;
      }
      __syncthreads();
      #pragma unroll
      for (int kk=0;kk<2;kk++){
        bf16x8 av[4], bv[4];
        #pragma unroll
        for (int mi=0;mi<4;mi++){
          int m = wm*64 + mi*16 + r;
          av[mi] = *(const bf16x8*)&sA[m*64 + (((kk*4 + g) ^ (m & 7)) * 8)];
        }
        #pragma unroll
        for (int ni=0;ni<4;ni++){
          int n = wn*64 + ni*16 + r;
          bv[ni] = *(const bf16x8*)&sB[n*64 + (((kk*4 + g) ^ (n & 7)) * 8)];
        }
        #pragma unroll
        for (int mi=0;mi<4;mi++)
          #pragma unroll
          for (int ni=0;ni<4;ni++)
            acc[mi][ni] = __builtin_amdgcn_mfma_f32_16x16x32_bf16(av[mi], bv[ni], acc[mi][ni], 0, 0, 0);
      }
    }
  }
  #pragma unroll
  for (int mi=0;mi<4;mi++)
    #pragma unroll
    for (int ni=0;ni<4;ni++)
      #pragma unroll
      for (int jj=0;jj<4;jj++){
        int m = bm*128 + wm*64 + mi*16 + g*4 + jj;
        int n = bn*128 + wn*64 + ni*16 + r;
        C[(size_t)m * N + n] = acc[mi][ni][jj];
      }
}

// ---------------- host ----------------
static void fold_key(uint32_t i, uint32_t& o0, uint32_t& o1){
  uint32_t x0 = 0, x1 = i;
  tf2x32(0u, 42u, x0, x1);
  o0 = x0; o1 = x1;
}

extern "C" void kernel_launch(void* const* d_in, const int* in_sizes, int n_in,
                              void* d_out, int out_size, void* d_ws, size_t ws_size,
                              hipStream_t stream)
{
  const int*   idx       = (const int*)  d_in[0];
  const float* wte       = (const float*)d_in[1];
  const float* rb_ln_g   = (const float*)d_in[2];
  const float* rb_ln_b   = (const float*)d_in[3];
  const float* rb_fc_w   = (const float*)d_in[4];
  const float* rb_fc_b   = (const float*)d_in[5];
  const float* rb_proj_w = (const float*)d_in[6];
  const float* rb_proj_b = (const float*)d_in[7];
  const float* lnf_g     = (const float*)d_in[8];
  const float* lnf_b     = (const float*)d_in[9];
  const float* lm_head_w = (const float*)d_in[10];
  const float* mb_ln_g   = (const float*)d_in[11];
  const float* mb_ln_b   = (const float*)d_in[12];
  const float* mb_fc_w   = (const float*)d_in[13];
  const float* mb_fc_b   = (const float*)d_in[14];
  const float* mb_proj_w = (const float*)d_in[15];
  const float* mb_proj_b = (const float*)d_in[16];
  const float* op_w      = (const float*)d_in[17];
  const float* op_b      = (const float*)d_in[18];
  const float* lns_g     = (const float*)d_in[19];
  const float* lns_b     = (const float*)d_in[20];
  const float* heads_w   = (const float*)d_in[21];

  const size_t TD = (size_t)T_TOK * DIM;
  const size_t DV = (size_t)DIM * VOCAB;

  float* X = (float*)d_ws;
  float* Y = X + TD;                         // kept for layout compat (unused)
  unsigned short* Xbf = (unsigned short*)(Y + TD);
  unsigned short* Xlo = Xbf + TD;
  unsigned short* BtFh = Xlo + TD;
  unsigned short* BtFl = BtFh + DV;
  size_t need_big = (size_t)((char*)(BtFl + DV) - (char*)d_ws);
  bool big = ws_size >= need_big;

  char* ob = (char*)d_out;
  float* OUT = (float*)d_out;
  unsigned short* Hh     = (unsigned short*)(ob);
  unsigned short* Hl     = Hh + TD;
  unsigned short* ACTh   = (unsigned short*)(ob + ((size_t)16<<20));
  unsigned short* ACTl   = ACTh + TD*4;
  unsigned short* Btfc_h = (unsigned short*)(ob + ((size_t)72<<20));
  unsigned short* Btfc_l = Btfc_h + (size_t)3072*DIM;
  unsigned short* Btpj_h = (unsigned short*)(ob + ((size_t)84<<20));
  unsigned short* Btpj_l = Btpj_h + (size_t)3072*DIM;
  unsigned short* BtS    = (unsigned short*)(ob + ((size_t)96<<20));
  unsigned short* Btop_h = (unsigned short*)(ob + ((size_t)152<<20));
  unsigned short* Btop_l = Btop_h + (size_t)DIM*DIM;
  float* MERGE = (float*)(ob + ((size_t)160<<20));
  unsigned long long* ROWBEST = (unsigned long long*)(ob + ((size_t)176<<20));
  int* COUNT = (int*)(ROWBEST + T_TOK);      // adjacent -> one memset covers both
  int* PLIST = COUNT + 1;
  float* PART = (float*)(ob + ((size_t)192<<20));   // 3 x TD f32 = 37.75 MB

  dim3 blk(256);
  dim3 blk16(1024);

  // 1) embed + rb_ln
  k_embed_ln<<<T_TOK, blk, 0, stream>>>(idx, wte, rb_ln_g, rb_ln_b, X, Hh, Hl);
  // 2) weight transposes for prologue MLP
  k_wt_t<true><<<dim3(12,48), blk, 0, stream>>>(rb_fc_w,   Btfc_h, Btfc_l, DIM,  3072);
  k_wt_t<true><<<dim3(48,12), blk, 0, stream>>>(rb_proj_w, Btpj_h, Btpj_l, 3072, DIM);
  // 3) fc (split) + bias + qgelu -> ACT hi/lo  (256^2 16-wave, SMAX=24)
  k_hgemm256<12,3,ST_HILO,false,true,true><<<192, blk16, 0, stream>>>(
      Hh, Hl, Btfc_h, Btfc_l, nullptr, ACTh, ACTl, rb_fc_b, 0u,0u, nullptr, 3072, 24);
  // 4) proj: seg-split (3x192 blocks) -> partials; fused reduce+residual+lnf
  k_hgemm_seg<48><<<576, blk, 0, stream>>>(ACTh, ACTl, Btpj_h, Btpj_l, PART, DIM);
  k_redln<<<T_TOK, blk, 0, stream>>>(PART, rb_proj_b, X, lnf_g, lnf_b, X, Xbf, Xlo);

  for (int i = 0; i < NLAYER; ++i){
    int j = i + 1;
    uint32_t kf0, kf1; fold_key((uint32_t)i, kf0, kf1);

    hipMemsetAsync(ROWBEST, 0, (size_t)T_TOK*8 + 4, stream);   // ROWBEST + COUNT

    const float* hw = (i == 0) ? lm_head_w : heads_w + (size_t)(i-1)*DV;
    k_wt_t<false><<<dim3(12,500), blk, 0, stream>>>(hw, BtS, nullptr, DIM, VOCAB);
    // sampling head: persistent 256^2 16-wave GEMM + fused gumbel-argmax
    // (256 blocks = exactly 1/CU full residency)
    k_hgemm256<12,1,ST_SAMPLE,false,false,false><<<256, blk16, 0, stream>>>(
        Xbf, Xbf, BtS, BtS, nullptr, nullptr, nullptr, nullptr, kf0, kf1, ROWBEST, VOCAB, 250);

    k_mask<<<T_TOK/256, blk, 0, stream>>>(ROWBEST, idx, j, COUNT, PLIST);
    k_merge<<<64, blk, 0, stream>>>(X, PLIST, COUNT,
        mb_ln_g + (size_t)i*1536, mb_ln_b + (size_t)i*1536,
        mb_fc_w + (size_t)i*1536*3072, mb_fc_b + (size_t)i*3072,
        mb_proj_w + (size_t)i*3072*DIM, mb_proj_b + (size_t)i*DIM, MERGE, j);
    k_scatter<<<64, blk, 0, stream>>>(X, Xbf, Xlo, MERGE, PLIST, COUNT, j);

    // op: seg-split -> partials; fused reduce+bias+lns
    k_wt_t<true><<<dim3(12,12), blk, 0, stream>>>(op_w + (size_t)i*DIM*DIM, Btop_h, Btop_l, DIM, DIM);
    k_hgemm_seg<12><<<576, blk, 0, stream>>>(Xbf, Xlo, Btop_h, Btop_l, PART, DIM);
    k_redln<<<T_TOK, blk, 0, stream>>>(PART, op_b + (size_t)i*DIM, nullptr,
        lns_g + (size_t)i*DIM, lns_b + (size_t)i*DIM, X, Xbf, Xlo);
  }

  // final head (split-bf16, f32-grade) -> d_out, NT stores, persistent.
  if (big){
    k_wt_t<true><<<dim3(12,500), blk, 0, stream>>>(heads_w + (size_t)3*DV, BtFh, BtFl, DIM, VOCAB);
    k_hgemm256<12,3,ST_F32,true,false,false><<<256, blk16, 0, stream>>>(
        Xbf, Xlo, BtFh, BtFl, OUT, nullptr, nullptr, nullptr, 0u, 0u, nullptr, VOCAB, 250);
  } else {
    k_gemm_old<<<dim3(VOCAB/128, T_TOK/128), blk, 0, stream>>>(
        X, heads_w + (size_t)3*DV, OUT, T_TOK, VOCAB, DIM);
  }
}

// Round 13
// 2490.039 us; speedup vs baseline: 1.0727x; 1.0727x over previous
//
#include <hip/hip_runtime.h>
#include <cstdint>
#include <cstddef>

#define T_TOK 4096
#define DIM   768
#define VOCAB 32000
#define NLAYER 4
#define HALF_TV 65536000u   // T*V/2

typedef short bf16x8 __attribute__((ext_vector_type(8)));
typedef float f32x4  __attribute__((ext_vector_type(4)));
typedef float f32x4v __attribute__((ext_vector_type(4)));

// ---------------- threefry2x32 (exact JAX semantics) ----------------
__host__ __device__ inline void tf2x32(uint32_t k0, uint32_t k1, uint32_t& v0, uint32_t& v1){
  uint32_t ks2 = k0 ^ k1 ^ 0x1BD11BDAu;
  uint32_t x0 = v0 + k0, x1 = v1 + k1;
#define TFR(R) { x0 += x1; x1 = (x1<<R)|(x1>>(32-R)); x1 ^= x0; }
  TFR(13) TFR(15) TFR(26) TFR(6)
  x0 += k1;  x1 += ks2 + 1u;
  TFR(17) TFR(29) TFR(16) TFR(24)
  x0 += ks2; x1 += k0 + 2u;
  TFR(13) TFR(15) TFR(26) TFR(6)
  x0 += k0;  x1 += k1 + 3u;
  TFR(17) TFR(29) TFR(16) TFR(24)
  x0 += k1;  x1 += ks2 + 4u;
  TFR(13) TFR(15) TFR(26) TFR(6)
  x0 += ks2; x1 += k0 + 5u;
#undef TFR
  v0 = x0; v1 = x1;
}

// -ln(u) with RELATIVE accuracy, u = k ? k*2^-23 : FLT_MIN.
__device__ inline float neglog_u(uint32_t k){
  float L;
  if (k >= 0x780000u){
    float x = (float)(0x800000u - k) * 1.1920928955078125e-7f;   // 1-u, exact
    L = x * fmaf(x, fmaf(x, fmaf(x, 0.25f, 0.3333333333333f), 0.5f), 1.0f);
  } else {
    float l2k = __builtin_amdgcn_logf((float)k);                 // log2(k)
    L = 0.69314718055994531f * (23.0f - l2k);
    if (k == 0u) L = 87.33654475055310898f;                      // 126*ln2
  }
  return L;
}

__device__ inline void gumbel_pair(uint32_t kf0, uint32_t kf1, uint32_t t_up, uint32_t v,
                                   float& gu, float& gd){
  uint32_t m = t_up * (uint32_t)VOCAB + v;
  uint32_t x0 = m, x1 = m + HALF_TV;
  tf2x32(kf0, kf1, x0, x1);
  float Lu = neglog_u(x0 >> 9);
  float Ld = neglog_u(x1 >> 9);
  gu = -0.69314718055994531f * __builtin_amdgcn_logf(Lu);
  gd = -0.69314718055994531f * __builtin_amdgcn_logf(Ld);
}

// ---------------- helpers ----------------
__device__ inline unsigned short f2bf(float f){  // RNE f32->bf16
  uint32_t u = __float_as_uint(f);
  return (unsigned short)((u + 0x7FFFu + ((u >> 16) & 1u)) >> 16);
}
__device__ inline float bf2f(unsigned short h){
  return __uint_as_float(((uint32_t)h) << 16);
}
__device__ inline void cvt8(const float* f, bool lo, unsigned short* out){
  #pragma unroll
  for (int e=0;e<8;e++){
    float x = f[e];
    unsigned short h = f2bf(x);
    if (lo) h = f2bf(x - bf2f(h));
    out[e] = h;
  }
}
__device__ inline float blockReduceSum(float v){
  __shared__ float red[4];
  #pragma unroll
  for (int off=32; off>0; off>>=1) v += __shfl_down(v, off);
  int w = threadIdx.x >> 6;
  __syncthreads();
  if ((threadIdx.x & 63) == 0) red[w] = v;
  __syncthreads();
  return red[0] + red[1] + red[2] + red[3];
}

__device__ inline void gload16(const void* g, void* l){
  __builtin_amdgcn_global_load_lds(
      (const __attribute__((address_space(1))) unsigned int*)g,
      (__attribute__((address_space(3))) unsigned int*)l, 16, 0, 0);
}

enum { ST_F32 = 0, ST_HILO = 1, ST_SAMPLE = 2 };

// =====================================================================
// k_hgemm256: PERSISTENT 256x256-tile GEMM, 1024 threads = 16 waves
// (4M x 4N), wave C = 64x64, 4 waves/SIMD.  Inner loop = r8 structure
// (measured 1112 TF / MfmaUtil 52%): double-buffered 128KB LDS, tile
// t+1 staged at tile-t start, ONE barrier per K-tile, XOR swizzle
// (conflict-free, PMC=0).  Persistent (512 blocks): each block sweeps
// s += nloc keeping ONE bm (A-panel L2-resident per XCD); next
// super-tile's stage(0) issued BEFORE the epilogue.
// LOCAL-OPTIMUM, triple-refuted variants (do not retry):
//   r6: 8 waves / 2 per SIMD free-running   -> MfmaUtil 43 (worse)
//   r9: per-phase block-wide barriers        -> MfmaUtil 39 (worse)
//   r12: batched 12-read bursts + 256 blocks -> MfmaUtil 45, FETCH +13%
// M rows slab-interleaved {t, t+2048} at 16-row granularity.
// =====================================================================
template<int KSTEPS, int NSEG, int STORE, bool NTST, bool BIAS, bool QGELU>
__global__ __launch_bounds__(1024, 4) void k_hgemm256(
    const unsigned short* __restrict__ A0, const unsigned short* __restrict__ A1,
    const unsigned short* __restrict__ B0, const unsigned short* __restrict__ B2,
    float* __restrict__ C, unsigned short* __restrict__ Ch, unsigned short* __restrict__ Cl,
    const float* __restrict__ bias, uint32_t kf0, uint32_t kf1,
    unsigned long long* __restrict__ row_best, int N, int SMAX)
{
  constexpr int K  = KSTEPS * 64;
  constexpr int NT = NSEG * KSTEPS;
  __shared__ unsigned short sAll[65536];   // 2 buf x (A 32KB + B 32KB) = 128 KB

  const int t = threadIdx.x;
  const int w = t >> 6, l = t & 63;
  const int wm = w >> 2, wn = w & 3;       // 4M x 4N waves
  const int g = l >> 4, r = l & 15;

  const int xcd  = blockIdx.x & 7;
  const int nloc = gridDim.x >> 3;
  const int lcl  = blockIdx.x >> 3;

  // lane-invariant staging row bases (tile-local)
  int abase[2], nbase[2];
  #pragma unroll
  for (int p=0;p<2;p++){
    int mr = p*128 + (t >> 3);             // tile-local row 0..255
    int blk = mr >> 4;
    abase[p] = ((blk>>1)<<4) + (mr & 15) + ((blk & 1) ? 2048 : 0);
    nbase[p] = p*128 + (t >> 3);
  }
  const int swz  = ((t & 7) ^ ((t >> 3) & 7)) << 3;   // pre-swizzled k-chunk
  const int ldst = t * 16;                              // lane-linear LDS bytes

  auto stage = [&](int vt, int bm_, int bn_){
    char* base = (char*)sAll + (vt & 1) * 65536;
    int seg = (NSEG == 1) ? 0 : (vt / KSTEPS);
    int k0  = ((NSEG == 1) ? vt : (vt % KSTEPS)) * 64;
    const unsigned short* Ap = (seg == 1) ? A1 : A0;
    const unsigned short* Bp = (seg == 2) ? B2 : B0;
    #pragma unroll
    for (int p=0;p<2;p++)
      gload16(Ap + (size_t)(bm_*128 + abase[p]) * K + k0 + swz, base + p*16384 + ldst);
    #pragma unroll
    for (int p=0;p<2;p++)
      gload16(Bp + (size_t)(bn_*256 + nbase[p]) * K + k0 + swz, base + 32768 + p*16384 + ldst);
  };

  int s = lcl;
  if (s >= SMAX) return;
  int bm = xcd*2 + (s & 1), bn = s >> 1;
  stage(0, bm, bn);
  __syncthreads();                          // first tile resident

  while (true) {
    f32x4 acc[4][4] = {};
    for (int vt = 0; vt < NT; ++vt){
      if (vt + 1 < NT) stage(vt + 1, bm, bn);   // full-tile prefetch lead
      const char* sA = (const char*)sAll + (vt & 1) * 65536;
      const char* sB = sA + 32768;
      #pragma unroll
      for (int kk=0;kk<2;kk++){
        bf16x8 bv[4], av[4];
        #pragma unroll
        for (int ni=0;ni<4;ni++){
          int tr = wn*64 + ni*16 + r;
          bv[ni] = *(const bf16x8*)(sB + tr*128 + (((kk*4+g) ^ (r&7))<<4));
        }
        #pragma unroll
        for (int q=0;q<4;q++){
          int tr = wm*64 + q*16 + r;
          av[q] = *(const bf16x8*)(sA + tr*128 + (((kk*4+g) ^ (r&7))<<4));
        }
        __builtin_amdgcn_s_setprio(1);
        #pragma unroll
        for (int q=0;q<4;q++)
          #pragma unroll
          for (int ni=0;ni<4;ni++)
            acc[q][ni] = __builtin_amdgcn_mfma_f32_16x16x32_bf16(av[q], bv[ni], acc[q][ni], 0, 0, 0);
        __builtin_amdgcn_s_setprio(0);
      }
      __syncthreads();                      // vmcnt+lgkm drain + barrier
    }

    // Prefetch the NEXT super-tile's first K-tile BEFORE the epilogue:
    // epilogue VALU fully hides the HBM latency.  buf0's last reader was
    // vt=NT-2 (NT even), already barrier-separated -> safe.
    int ns = s + nloc;
    bool more = (ns < SMAX);
    int nbm = 0, nbn = 0;
    if (more){ nbm = xcd*2 + (ns & 1); nbn = ns >> 1; stage(0, nbm, nbn); }

    if constexpr (STORE == ST_SAMPLE){
      #pragma unroll
      for (int mi=0; mi<4; mi+=2){
        int row16 = (wm*2 + (mi>>1)) * 16;  // even fragment -> up slab
        #pragma unroll
        for (int jj=0;jj<4;jj++){
          uint32_t t_up = bm*128 + row16 + g*4 + jj;   // < 2048
          unsigned long long bu = 0ull, bd = 0ull;
          #pragma unroll
          for (int ni=0;ni<4;ni++){
            uint32_t v = bn*256 + wn*64 + ni*16 + r;
            float gu, gd;
            gumbel_pair(kf0, kf1, t_up, v, gu, gd);
            float vu = acc[mi][ni][jj]   + gu;
            float vd = acc[mi+1][ni][jj] + gd;
            uint32_t fu = __float_as_uint(vu); fu = (fu & 0x80000000u) ? ~fu : (fu | 0x80000000u);
            uint32_t fd = __float_as_uint(vd); fd = (fd & 0x80000000u) ? ~fd : (fd | 0x80000000u);
            unsigned long long pu = ((unsigned long long)fu << 32) | (unsigned long long)(~v);
            unsigned long long pd = ((unsigned long long)fd << 32) | (unsigned long long)(~v);
            if (pu > bu) bu = pu;
            if (pd > bd) bd = pd;
          }
          #pragma unroll
          for (int off=1; off<16; off<<=1){
            unsigned int l0 = (unsigned int)bu, h0 = (unsigned int)(bu>>32);
            unsigned int l1 = __shfl_xor(l0, off), h1 = __shfl_xor(h0, off);
            unsigned long long o = ((unsigned long long)h1 << 32) | (unsigned long long)l1;
            if (o > bu) bu = o;
            l0 = (unsigned int)bd; h0 = (unsigned int)(bd>>32);
            l1 = __shfl_xor(l0, off); h1 = __shfl_xor(h0, off);
            o = ((unsigned long long)h1 << 32) | (unsigned long long)l1;
            if (o > bd) bd = o;
          }
          if (r == 0){
            atomicMax(&row_best[t_up], bu);
            atomicMax(&row_best[t_up + 2048], bd);
          }
        }
      }
    } else {
      #pragma unroll
      for (int mi=0;mi<4;mi++){
        int fb = wm*4 + mi;
        int mbase = bm*128 + ((fb>>1)<<4) + ((fb & 1) ? 2048 : 0);
        #pragma unroll
        for (int ni=0;ni<4;ni++){
          int n = bn*256 + wn*64 + ni*16 + r;
          float bv_ = BIAS ? bias[n] : 0.0f;
          #pragma unroll
          for (int jj=0;jj<4;jj++){
            int m = mbase + g*4 + jj;
            float v = acc[mi][ni][jj] + bv_;
            if constexpr (QGELU) v = v / (1.0f + expf(-1.702f * v));
            if constexpr (STORE == ST_F32){
              if constexpr (NTST) __builtin_nontemporal_store(v, &C[(size_t)m * N + n]);
              else                C[(size_t)m * N + n] = v;
            } else {
              unsigned short h = f2bf(v);
              Ch[(size_t)m * N + n] = h;
              Cl[(size_t)m * N + n] = f2bf(v - bf2f(h));
            }
          }
        }
      }
    }

    if (!more) return;
    __syncthreads();                        // next tile's stage(0) visible
    s = ns; bm = nbm; bn = nbn;
  }
}

// =====================================================================
// k_hgemm_seg: 128^2-tile dbuf GEMM, ONE split-bf16 segment per block
// (seg0 = Ah*Bh, seg1 = Al*Bh, seg2 = Ah*Bl) -> f32 partials; 3x grid
// => full chip for small-N shapes (proj/op).  Deterministic reduce in
// k_redln (order p0+p1+p2).
// =====================================================================
template<int KSTEPS>
__global__ __launch_bounds__(256) void k_hgemm_seg(
    const unsigned short* __restrict__ Ah, const unsigned short* __restrict__ Al,
    const unsigned short* __restrict__ Bh, const unsigned short* __restrict__ Bl,
    float* __restrict__ Part, int N)
{
  constexpr int K  = KSTEPS * 64;
  constexpr int NT = KSTEPS;
  __shared__ unsigned short sAll[2 * 16 * 1024];   // 2 buf x (A 16KB + B 16KB)

  const int t = threadIdx.x;
  const int wave = t >> 6, lane = t & 63;
  const int wm = wave >> 1, wn = wave & 1;
  const int g = lane >> 4, r = lane & 15;
  const int lr = lane >> 3, lc = lane & 7;

  int bps = (N >> 7) * 32;                  // blocks per seg
  int seg = blockIdx.x / bps;
  int bid = blockIdx.x % bps;
  const unsigned short* Ap = (seg == 1) ? Al : Ah;
  const unsigned short* Bp = (seg == 2) ? Bl : Bh;
  float* C = Part + (size_t)seg * T_TOK * N;

  int xcd = bid & 7, c = bid >> 3;
  int bm = xcd*4 + (c & 3);
  int bn = c >> 2;

  f32x4 acc[4][4] = {};

  size_t arow[4], brow[4];
  #pragma unroll
  for (int p=0;p<4;p++){
    int mr = p*32 + wave*8 + lr;
    int blk = mr >> 4;
    arow[p] = (size_t)(bm*64 + ((blk>>1)<<4) + (mr & 15) + ((blk & 1) ? 2048 : 0)) * K;
    brow[p] = (size_t)(bn*128 + mr) * K;
  }
  const int swz  = (lc ^ lr) << 3;
  const int ldst = (wave*8 + lr)*128 + lc*16;

  auto stage = [&](int vt){
    char* base = (char*)sAll + (vt & 1) * 32768;
    int k0 = vt * 64;
    #pragma unroll
    for (int p=0;p<4;p++){
      gload16(Ap + arow[p] + k0 + swz, base + p*4096 + ldst);
      gload16(Bp + brow[p] + k0 + swz, base + 16384 + p*4096 + ldst);
    }
  };

  stage(0);
  __syncthreads();

  for (int vt = 0; vt < NT; ++vt){
    if (vt + 1 < NT) stage(vt + 1);
    const char* sA = (const char*)sAll + (vt & 1) * 32768;
    const char* sB = sA + 16384;
    #pragma unroll
    for (int kk=0;kk<2;kk++){
      bf16x8 av[4], bv[4];
      #pragma unroll
      for (int mi=0;mi<4;mi++){
        int tr = wm*64 + mi*16 + r;
        av[mi] = *(const bf16x8*)(sA + tr*128 + (((kk*4+g) ^ (r&7))<<4));
      }
      #pragma unroll
      for (int ni=0;ni<4;ni++){
        int tr = wn*64 + ni*16 + r;
        bv[ni] = *(const bf16x8*)(sB + tr*128 + (((kk*4+g) ^ (r&7))<<4));
      }
      #pragma unroll
      for (int mi=0;mi<4;mi++)
        #pragma unroll
        for (int ni=0;ni<4;ni++)
          acc[mi][ni] = __builtin_amdgcn_mfma_f32_16x16x32_bf16(av[mi], bv[ni], acc[mi][ni], 0, 0, 0);
    }
    __syncthreads();
  }

  #pragma unroll
  for (int mi=0;mi<4;mi++){
    int blk2 = wm*4 + mi;
    int mbase = bm*64 + ((blk2>>1)<<4) + ((blk2 & 1) ? 2048 : 0);
    #pragma unroll
    for (int ni=0;ni<4;ni++){
      int n = bn*128 + wn*64 + ni*16 + r;
      #pragma unroll
      for (int jj=0;jj<4;jj++){
        int m = mbase + g*4 + jj;
        C[(size_t)m * N + n] = acc[mi][ni][jj];
      }
    }
  }
}

// =====================================================================
// k_redln: deterministic seg-sum + bias (+res) + LayerNorm, fused.
// =====================================================================
__global__ __launch_bounds__(256) void k_redln(
    const float* __restrict__ P, const float* __restrict__ bias,
    const float* __restrict__ res,
    const float* __restrict__ g, const float* __restrict__ b,
    float* __restrict__ X, unsigned short* __restrict__ Xbf,
    unsigned short* __restrict__ Xlo)
{
  const size_t TD1 = (size_t)T_TOK * DIM;
  int row = blockIdx.x;
  float v[3];
  #pragma unroll
  for (int jj=0;jj<3;jj++){
    int d = threadIdx.x + jj*256;
    size_t o = (size_t)row*DIM + d;
    float x = P[o] + P[TD1 + o] + P[2*TD1 + o] + bias[d];
    if (res) x += res[o];
    v[jj] = x;
  }
  float s = blockReduceSum(v[0]+v[1]+v[2]);
  float mean = s * (1.0f/DIM);
  float s2 = 0;
  #pragma unroll
  for (int jj=0;jj<3;jj++){ float d = v[jj]-mean; s2 += d*d; }
  s2 = blockReduceSum(s2);
  float rs = rsqrtf(s2 * (1.0f/DIM) + 1e-5f);
  #pragma unroll
  for (int jj=0;jj<3;jj++){
    int d = threadIdx.x + jj*256;
    size_t o = (size_t)row*DIM + d;
    float out = (v[jj]-mean)*rs*g[d] + b[d];
    X[o] = out;
    unsigned short h = f2bf(out);
    Xbf[o] = h;
    Xlo[o] = f2bf(out - bf2f(h));
  }
}

// ---------------- weight transpose + f32->bf16 (hi[/lo]) ----------------
template<bool SPLIT>
__global__ __launch_bounds__(256) void k_wt_t(const float* __restrict__ W,
    unsigned short* __restrict__ Bh, unsigned short* __restrict__ Bl, int K, int N)
{
  __shared__ unsigned short sH[64][72];
  __shared__ unsigned short sL[64][72];
  int kt = blockIdx.x, nt = blockIdx.y;
  int t = threadIdx.x;
  int kr = t >> 4, nc4 = (t & 15) * 4;
  #pragma unroll
  for (int p=0;p<4;p++){
    int k = p*16 + kr;
    f32x4v w = __builtin_nontemporal_load((const f32x4v*)&W[(size_t)(kt*64 + k) * N + nt*64 + nc4]);
    #pragma unroll
    for (int e=0;e<4;e++){
      unsigned short h = f2bf(w[e]);
      sH[nc4+e][k] = h;
      if (SPLIT) sL[nc4+e][k] = f2bf(w[e] - bf2f(h));
    }
  }
  __syncthreads();
  #pragma unroll
  for (int q=0;q<2;q++){
    int cid = t + q*256;
    int n = cid >> 3, ch = cid & 7;
    *(bf16x8*)&Bh[(size_t)(nt*64+n)*K + kt*64 + ch*8] = *(const bf16x8*)&sH[n][ch*8];
    if (SPLIT)
      *(bf16x8*)&Bl[(size_t)(nt*64+n)*K + kt*64 + ch*8] = *(const bf16x8*)&sL[n][ch*8];
  }
}

// ---------------- embed + LN ----------------
__global__ __launch_bounds__(256) void k_embed_ln(const int* __restrict__ idx,
    const float* __restrict__ wte, const float* __restrict__ g, const float* __restrict__ b,
    float* __restrict__ Xraw, unsigned short* __restrict__ Hh, unsigned short* __restrict__ Hl)
{
  int row = blockIdx.x;
  const float* src = wte + (size_t)idx[row] * DIM;
  float v[3];
  #pragma unroll
  for (int jj=0;jj<3;jj++) v[jj] = src[threadIdx.x + jj*256];
  float s = blockReduceSum(v[0]+v[1]+v[2]);
  float mean = s * (1.0f/DIM);
  float s2 = 0;
  #pragma unroll
  for (int jj=0;jj<3;jj++){ float d = v[jj]-mean; s2 += d*d; }
  s2 = blockReduceSum(s2);
  float rs = rsqrtf(s2 * (1.0f/DIM) + 1e-5f);
  #pragma unroll
  for (int jj=0;jj<3;jj++){
    int d = threadIdx.x + jj*256;
    Xraw[(size_t)row*DIM + d] = v[jj];
    float o = (v[jj]-mean)*rs*g[d] + b[d];
    unsigned short h = f2bf(o);
    Hh[(size_t)row*DIM + d] = h;
    Hl[(size_t)row*DIM + d] = f2bf(o - bf2f(h));
  }
}

// ---------------- mask compaction ----------------
__global__ void k_mask(const unsigned long long* __restrict__ row_best,
    const int* __restrict__ idx, int j, int* __restrict__ count, int* __restrict__ plist)
{
  int t = blockIdx.x * blockDim.x + threadIdx.x;
  if (t >= T_TOK) return;
  int v = (int)(~(uint32_t)(row_best[t] & 0xFFFFFFFFull));
  int tgt = (t < T_TOK-1) ? idx[t+1] : -1;
  if (v == tgt && t < T_TOK - j){
    int pos = atomicAdd(count, 1);
    plist[pos] = t;
  }
}

// ---------------- sparse merge MLP ----------------
__global__ __launch_bounds__(256) void k_merge(const float* __restrict__ X,
    const int* __restrict__ plist, const int* __restrict__ count,
    const float* __restrict__ lng, const float* __restrict__ lnb,
    const float* __restrict__ fcw, const float* __restrict__ fcb,
    const float* __restrict__ pjw, const float* __restrict__ pjb,
    float* __restrict__ mergebuf, int j)
{
  __shared__ float sh[1536 + 3072];
  int nb = *count;
  for (int bIdx = blockIdx.x; bIdx < nb; bIdx += gridDim.x){
    int p = plist[bIdx];
    const float* xp = X + (size_t)p * DIM;
    const float* x2 = X + (size_t)(p + j) * DIM;
    for (int d = threadIdx.x; d < 1536; d += 256)
      sh[d] = (d < DIM) ? xp[d] : x2[d - DIM];
    __syncthreads();
    float s = 0;
    for (int d = threadIdx.x; d < 1536; d += 256) s += sh[d];
    s = blockReduceSum(s);
    float mean = s * (1.0f/1536.0f);
    float s2 = 0;
    for (int d = threadIdx.x; d < 1536; d += 256){ float df = sh[d]-mean; s2 += df*df; }
    s2 = blockReduceSum(s2);
    float rs = rsqrtf(s2 * (1.0f/1536.0f) + 1e-5f);
    __syncthreads();
    for (int d = threadIdx.x; d < 1536; d += 256)
      sh[d] = (sh[d]-mean)*rs*lng[d] + lnb[d];
    __syncthreads();
    float* act = sh + 1536;
    #pragma unroll
    for (int jj=0;jj<12;jj++){
      int n = threadIdx.x + jj*256;
      float a = fcb[n];
      for (int k=0;k<1536;k++) a += sh[k]*fcw[(size_t)k*3072 + n];
      act[n] = a / (1.0f + expf(-1.702f*a));
    }
    __syncthreads();
    #pragma unroll
    for (int jj=0;jj<3;jj++){
      int d = threadIdx.x + jj*256;
      float a = pjb[d];
      for (int k=0;k<3072;k++) a += act[k]*pjw[(size_t)k*DIM + d];
      mergebuf[(size_t)bIdx*DIM + d] = x2[d] + a;
    }
    __syncthreads();
  }
}

__global__ void k_scatter(float* __restrict__ X, unsigned short* __restrict__ Xbf,
    unsigned short* __restrict__ Xlo, const float* __restrict__ mergebuf,
    const int* __restrict__ plist, const int* __restrict__ count, int j)
{
  int nb = *count;
  for (int bIdx = blockIdx.x; bIdx < nb; bIdx += gridDim.x){
    int p = plist[bIdx];
    for (int d = threadIdx.x; d < DIM; d += 256){
      float v = mergebuf[(size_t)bIdx*DIM + d];
      size_t o = (size_t)(p + j)*DIM + d;
      X[o] = v;
      unsigned short h = f2bf(v);
      Xbf[o] = h;
      Xlo[o] = f2bf(v - bf2f(h));
    }
  }
}

// ---------------- fallback final-head GEMM (f32 in, split-bf16) ----
__global__ __launch_bounds__(256) void k_gemm_old(
    const float* __restrict__ A, const float* __restrict__ B, float* __restrict__ C,
    int M, int N, int K)
{
  __shared__ unsigned short sA[128*64];
  __shared__ unsigned short sB[128*64];
  const int t = threadIdx.x;
  const int bn = blockIdx.x, bm = blockIdx.y;
  const int wave = t >> 6, lane = t & 63;
  const int wm = wave >> 1, wn = wave & 1;
  const int g = lane >> 4, r = lane & 15;
  f32x4 acc[4][4] = {};
  const int nK = K >> 6;
  const int aC = t & 7,  aM0 = t >> 3;
  const int bN0 = t & 31, bC = t >> 5;
  const float* Abase = A + (size_t)(bm*128) * K;
  const float* Bbase = B + (size_t)(bn*128);
  for (int seg = 0; seg < 3; ++seg) {
    const bool aLO = (seg == 1), bLO = (seg == 2);
    for (int kb = 0; kb < nK; ++kb) {
      const int k0 = kb << 6;
      __syncthreads();
      #pragma unroll
      for (int p=0;p<4;p++){
        int m = p*32 + aM0;
        const float* src = Abase + (size_t)m * K + k0 + aC*8;
        float ff[8];
        *(float4*)(ff)   = *(const float4*)(src);
        *(float4*)(ff+4) = *(const float4*)(src+4);
        unsigned short hh[8];
        cvt8(ff, aLO, hh);
        *(bf16x8*)&sA[m*64 + ((aC ^ (m & 7)) * 8)] = *(bf16x8*)hh;
      }
      #pragma unroll
      for (int p=0;p<4;p++){
        int n = p*32 + bN0;
        float ff[8];
        const float* src = Bbase + (size_t)(k0 + bC*8) * N + n;
        #pragma unroll
        for (int e=0;e<8;e++) ff[e] = src[(size_t)e * N];
        unsigned short hh[8];
        cvt8(ff, bLO, hh);
        *(bf16x8*)&sB[n*64 + ((bC ^ (n & 7)) * 8)] = *(bf16x8*)hh;
      }
      __syncthreads();
      #pragma unroll
      for (int kk=0;kk<2;kk++){
        bf16x8 av[4], bv[4];
        #pragma unroll
        for (int mi=0;mi<4;mi++){
          int m = wm*64 + mi*16 + r;
          av[mi] = *(const bf16x8*)&sA[m*64 + (((kk*4 + g) ^ (m & 7)) * 8)];
        }
        #pragma unroll
        for (int ni=0;ni<4;ni++){
          int n = wn*64 + ni*16 + r;
          bv[ni] = *(const bf16x8*)&sB[n*64 + (((kk*4 + g) ^ (n & 7)) * 8)];
        }
        #pragma unroll
        for (int mi=0;mi<4;mi++)
          #pragma unroll
          for (int ni=0;ni<4;ni++)
            acc[mi][ni] = __builtin_amdgcn_mfma_f32_16x16x32_bf16(av[mi], bv[ni], acc[mi][ni], 0, 0, 0);
      }
    }
  }
  #pragma unroll
  for (int mi=0;mi<4;mi++)
    #pragma unroll
    for (int ni=0;ni<4;ni++)
      #pragma unroll
      for (int jj=0;jj<4;jj++){
        int m = bm*128 + wm*64 + mi*16 + g*4 + jj;
        int n = bn*128 + wn*64 + ni*16 + r;
        C[(size_t)m * N + n] = acc[mi][ni][jj];
      }
}

// ---------------- host ----------------
static void fold_key(uint32_t i, uint32_t& o0, uint32_t& o1){
  uint32_t x0 = 0, x1 = i;
  tf2x32(0u, 42u, x0, x1);
  o0 = x0; o1 = x1;
}

extern "C" void kernel_launch(void* const* d_in, const int* in_sizes, int n_in,
                              void* d_out, int out_size, void* d_ws, size_t ws_size,
                              hipStream_t stream)
{
  const int*   idx       = (const int*)  d_in[0];
  const float* wte       = (const float*)d_in[1];
  const float* rb_ln_g   = (const float*)d_in[2];
  const float* rb_ln_b   = (const float*)d_in[3];
  const float* rb_fc_w   = (const float*)d_in[4];
  const float* rb_fc_b   = (const float*)d_in[5];
  const float* rb_proj_w = (const float*)d_in[6];
  const float* rb_proj_b = (const float*)d_in[7];
  const float* lnf_g     = (const float*)d_in[8];
  const float* lnf_b     = (const float*)d_in[9];
  const float* lm_head_w = (const float*)d_in[10];
  const float* mb_ln_g   = (const float*)d_in[11];
  const float* mb_ln_b   = (const float*)d_in[12];
  const float* mb_fc_w   = (const float*)d_in[13];
  const float* mb_fc_b   = (const float*)d_in[14];
  const float* mb_proj_w = (const float*)d_in[15];
  const float* mb_proj_b = (const float*)d_in[16];
  const float* op_w      = (const float*)d_in[17];
  const float* op_b      = (const float*)d_in[18];
  const float* lns_g     = (const float*)d_in[19];
  const float* lns_b     = (const float*)d_in[20];
  const float* heads_w   = (const float*)d_in[21];

  const size_t TD = (size_t)T_TOK * DIM;
  const size_t DV = (size_t)DIM * VOCAB;

  float* X = (float*)d_ws;
  float* Y = X + TD;                         // kept for layout compat (unused)
  unsigned short* Xbf = (unsigned short*)(Y + TD);
  unsigned short* Xlo = Xbf + TD;
  unsigned short* BtFh = Xlo + TD;
  unsigned short* BtFl = BtFh + DV;
  size_t need_big = (size_t)((char*)(BtFl + DV) - (char*)d_ws);
  bool big = ws_size >= need_big;

  char* ob = (char*)d_out;
  float* OUT = (float*)d_out;
  unsigned short* Hh     = (unsigned short*)(ob);
  unsigned short* Hl     = Hh + TD;
  unsigned short* ACTh   = (unsigned short*)(ob + ((size_t)16<<20));
  unsigned short* ACTl   = ACTh + TD*4;
  unsigned short* Btfc_h = (unsigned short*)(ob + ((size_t)72<<20));
  unsigned short* Btfc_l = Btfc_h + (size_t)3072*DIM;
  unsigned short* Btpj_h = (unsigned short*)(ob + ((size_t)84<<20));
  unsigned short* Btpj_l = Btpj_h + (size_t)3072*DIM;
  unsigned short* BtS    = (unsigned short*)(ob + ((size_t)96<<20));
  unsigned short* Btop_h = (unsigned short*)(ob + ((size_t)152<<20));
  unsigned short* Btop_l = Btop_h + (size_t)DIM*DIM;
  float* MERGE = (float*)(ob + ((size_t)160<<20));
  unsigned long long* ROWBEST = (unsigned long long*)(ob + ((size_t)176<<20));
  int* COUNT = (int*)(ROWBEST + T_TOK);      // adjacent -> one memset covers both
  int* PLIST = COUNT + 1;
  float* PART = (float*)(ob + ((size_t)192<<20));   // 3 x TD f32 = 37.75 MB

  dim3 blk(256);
  dim3 blk16(1024);

  // 1) embed + rb_ln
  k_embed_ln<<<T_TOK, blk, 0, stream>>>(idx, wte, rb_ln_g, rb_ln_b, X, Hh, Hl);
  // 2) weight transposes for prologue MLP
  k_wt_t<true><<<dim3(12,48), blk, 0, stream>>>(rb_fc_w,   Btfc_h, Btfc_l, DIM,  3072);
  k_wt_t<true><<<dim3(48,12), blk, 0, stream>>>(rb_proj_w, Btpj_h, Btpj_l, 3072, DIM);
  // 3) fc (split) + bias + qgelu -> ACT hi/lo  (256^2 16-wave, SMAX=24)
  k_hgemm256<12,3,ST_HILO,false,true,true><<<192, blk16, 0, stream>>>(
      Hh, Hl, Btfc_h, Btfc_l, nullptr, ACTh, ACTl, rb_fc_b, 0u,0u, nullptr, 3072, 24);
  // 4) proj: seg-split (3x192 blocks) -> partials; fused reduce+residual+lnf
  k_hgemm_seg<48><<<576, blk, 0, stream>>>(ACTh, ACTl, Btpj_h, Btpj_l, PART, DIM);
  k_redln<<<T_TOK, blk, 0, stream>>>(PART, rb_proj_b, X, lnf_g, lnf_b, X, Xbf, Xlo);

  for (int i = 0; i < NLAYER; ++i){
    int j = i + 1;
    uint32_t kf0, kf1; fold_key((uint32_t)i, kf0, kf1);

    hipMemsetAsync(ROWBEST, 0, (size_t)T_TOK*8 + 4, stream);   // ROWBEST + COUNT

    const float* hw = (i == 0) ? lm_head_w : heads_w + (size_t)(i-1)*DV;
    k_wt_t<false><<<dim3(12,500), blk, 0, stream>>>(hw, BtS, nullptr, DIM, VOCAB);
    // sampling head: persistent 256^2 16-wave GEMM + fused gumbel-argmax
    k_hgemm256<12,1,ST_SAMPLE,false,false,false><<<512, blk16, 0, stream>>>(
        Xbf, Xbf, BtS, BtS, nullptr, nullptr, nullptr, nullptr, kf0, kf1, ROWBEST, VOCAB, 250);

    k_mask<<<T_TOK/256, blk, 0, stream>>>(ROWBEST, idx, j, COUNT, PLIST);
    k_merge<<<64, blk, 0, stream>>>(X, PLIST, COUNT,
        mb_ln_g + (size_t)i*1536, mb_ln_b + (size_t)i*1536,
        mb_fc_w + (size_t)i*1536*3072, mb_fc_b + (size_t)i*3072,
        mb_proj_w + (size_t)i*3072*DIM, mb_proj_b + (size_t)i*DIM, MERGE, j);
    k_scatter<<<64, blk, 0, stream>>>(X, Xbf, Xlo, MERGE, PLIST, COUNT, j);

    // op: seg-split -> partials; fused reduce+bias+lns
    k_wt_t<true><<<dim3(12,12), blk, 0, stream>>>(op_w + (size_t)i*DIM*DIM, Btop_h, Btop_l, DIM, DIM);
    k_hgemm_seg<12><<<576, blk, 0, stream>>>(Xbf, Xlo, Btop_h, Btop_l, PART, DIM);
    k_redln<<<T_TOK, blk, 0, stream>>>(PART, op_b + (size_t)i*DIM, nullptr,
        lns_g + (size_t)i*DIM, lns_b + (size_t)i*DIM, X, Xbf, Xlo);
  }

  // final head (split-bf16, f32-grade) -> d_out, NT stores, persistent.
  if (big){
    k_wt_t<true><<<dim3(12,500), blk, 0, stream>>>(heads_w + (size_t)3*DV, BtFh, BtFl, DIM, VOCAB);
    k_hgemm256<12,3,ST_F32,true,false,false><<<512, blk16, 0, stream>>>(
        Xbf, Xlo, BtFh, BtFl, OUT, nullptr, nullptr, nullptr, 0u, 0u, nullptr, VOCAB, 250);
  } else {
    k_gemm_old<<<dim3(VOCAB/128, T_TOK/128), blk, 0, stream>>>(
        X, heads_w + (size_t)3*DV, OUT, T_TOK, VOCAB, DIM);
  }
}